// Round 3
// baseline (865.543 us; speedup 1.0000x reference)
//
#include <hip/hip_runtime.h>
#include <math.h>

#define NN 10000
#define EE 320000
#define TILE 32

constexpr float INVS32  = 0.17677669529663687f;   // 1/sqrt(32)
constexpr float INVS160 = 0.07905694150420949f;   // 1/sqrt(160)
constexpr float INVS96  = 0.10206207261596575f;   // 1/sqrt(96)
constexpr float INVS3   = 0.5773502691896258f;    // 1/sqrt(3)
constexpr float INVS2   = 0.7071067811865476f;    // 1/sqrt(2)
constexpr float LN2     = 0.6931471805599453f;

__device__ __forceinline__ float sspf(float v) {
  return fmaxf(v, 0.f) + log1pf(expf(-fabsf(v))) - LN2;
}

// ---------------- sort-by-dst kernels ----------------
__global__ void hist_k(const int* __restrict__ ei, int* __restrict__ cnt) {
  int e = blockIdx.x * 256 + threadIdx.x;
  if (e < EE) atomicAdd(&cnt[ei[e]], 1);
}

__global__ __launch_bounds__(1024) void scan_k(const int* __restrict__ cnt,
                                               int* __restrict__ offv,
                                               int* __restrict__ cursor) {
  __shared__ int s[1024];
  const int t = threadIdx.x;
  int loc[10];
  int sum = 0;
#pragma unroll
  for (int jj = 0; jj < 10; ++jj) {
    int idx = t * 10 + jj;
    int c = (idx < NN) ? cnt[idx] : 0;
    loc[jj] = sum;
    sum += c;
  }
  s[t] = sum;
  __syncthreads();
  for (int d = 1; d < 1024; d <<= 1) {
    int v = (t >= d) ? s[t - d] : 0;
    __syncthreads();
    s[t] += v;
    __syncthreads();
  }
  const int excl = (t > 0) ? s[t - 1] : 0;
#pragma unroll
  for (int jj = 0; jj < 10; ++jj) {
    int idx = t * 10 + jj;
    if (idx < NN) {
      offv[idx]   = excl + loc[jj];
      cursor[idx] = excl + loc[jj];
    }
  }
  if (t == 0) offv[NN] = EE;
}

__global__ void scat_k(const int* __restrict__ ei, int* __restrict__ cursor,
                       int* __restrict__ order) {
  int e = blockIdx.x * 256 + threadIdx.x;
  if (e < EE) {
    int p = atomicAdd(&cursor[ei[e]], 1);
    order[p] = e;
  }
}

// ---------------- node-level precompute ----------------
__global__ __launch_bounds__(256) void node_prep_k(
    const float* __restrict__ x,
    const float* __restrict__ W0p, const float* __restrict__ b0p,
    const float* __restrict__ W1p,
    const float* __restrict__ W0n, const float* __restrict__ b0n,
    const float* __restrict__ W1n,
    const float* __restrict__ G1, const float* __restrict__ g1b,
    const float* __restrict__ G2, const float* __restrict__ g2b,
    const float* __restrict__ L1,
    float* __restrict__ p1w, float* __restrict__ x0nw, float* __restrict__ x1nw,
    float* __restrict__ Aw, float* __restrict__ Bw)
{
  const int wv   = threadIdx.x >> 6;
  const int lane = threadIdx.x & 63;
  const int n    = blockIdx.x * 4 + wv;
  const bool nv  = (n < NN);

  __shared__ float sX[4][160];
  __shared__ float sP0[4][64];
  __shared__ float sF0[4][96];
  __shared__ float sH1[4][96];
  __shared__ float sG[4][96];

  if (nv) {
    sX[wv][lane]      = x[n * 160 + lane];
    sX[wv][lane + 64] = x[n * 160 + lane + 64];
    if (lane < 32) sX[wv][lane + 128] = x[n * 160 + lane + 128];
  }
  __syncthreads();

  if (nv) {
    {
      float d = 0.f;
      for (int i = 0; i < 64; ++i) d += sX[wv][i] * W0p[i * 64 + lane];
      sP0[wv][lane] = d * 0.125f + b0p[lane];
      sF0[wv][lane] = sX[wv][lane];
    }
    for (int o = lane; o < 96; o += 64) {
      const int v = o / 3, i_ = o % 3;
      float d = 0.f;
      for (int u = 0; u < 32; ++u) d += sX[wv][64 + u * 3 + i_] * W1p[u * 32 + v];
      p1w[n * 96 + o] = d * INVS32;
    }
    if (lane < 32) {
      float s2 = 1e-12f;
#pragma unroll
      for (int i = 0; i < 3; ++i) { float t = sX[wv][64 + lane * 3 + i]; s2 += t * t; }
      sF0[wv][64 + lane] = sqrtf(s2);
    }
  }
  __syncthreads();

  if (nv) for (int o = lane; o < 96; o += 64) {
    float d = g1b[o];
    for (int i = 0; i < 96; ++i) d += sF0[wv][i] * G1[i * 96 + o];
    sH1[wv][o] = d / (1.f + expf(-d));
  }
  __syncthreads();

  if (nv) for (int o = lane; o < 96; o += 64) {
    float d = g2b[o];
    for (int i = 0; i < 96; ++i) d += sH1[wv][i] * G2[i * 96 + o];
    sG[wv][o] = d;
  }
  __syncthreads();

  if (nv) {
    {
      float d = 0.f;
      for (int i = 0; i < 64; ++i) d += sG[wv][i] * W0n[i * 64 + lane];
      x0nw[n * 64 + lane] = d * 0.125f + b0n[lane];
    }
    for (int o = lane; o < 96; o += 64) {
      const int v = o / 3, i_ = o % 3;
      float d = 0.f;
      for (int u = 0; u < 32; ++u)
        d += sX[wv][64 + u * 3 + i_] * sG[wv][64 + u] * W1n[u * 32 + v];
      x1nw[n * 96 + o] = d * INVS32;
    }
    if (lane < 32) {
      float a = 0.f, b = 0.f;
      for (int i = 0; i < 64; ++i) {
        a += sP0[wv][i] * L1[i * 32 + lane];
        b += sP0[wv][i] * L1[(64 + i) * 32 + lane];
      }
      Aw[n * 32 + lane] = a * INVS160;
      Bw[n * 32 + lane] = b * INVS160;
    }
  }
}

// ---------------- fused per-edge MLP + scatter kernel ----------------
// block = 256 threads, TILE=32 sorted edges. Computes hidden layers,
// w-GEMM into LDS (f32, never to HBM), then register-accumulates the 480
// output channels along the sorted edge walk, flushing at dst-run
// boundaries via atomicAdd into o480.
__global__ __launch_bounds__(256) void fused_edge_k(
    const float* __restrict__ edge_attr,
    const float* __restrict__ edge_sh,
    const int* __restrict__ ei,
    const float* __restrict__ F1, const float* __restrict__ L1,
    const float* __restrict__ F2, const float* __restrict__ L2,
    const float* __restrict__ p1w, const float* __restrict__ Aw,
    const float* __restrict__ Bw,
    const float* __restrict__ x0nw, const float* __restrict__ x1nw,
    const int* __restrict__ order,
    float* __restrict__ o480)
{
  const int s0  = blockIdx.x * TILE;
  const int tid = threadIdx.x;

  __shared__ float sEA[TILE][36];
  __shared__ float sIP[TILE][36];
  __shared__ float sHF[TILE][36];
  __shared__ float sHL[TILE][36];
  __shared__ float sXS0[TILE][64];
  __shared__ float sXS1[TILE][96];
  __shared__ float sSH[TILE][4];
  __shared__ float sW[TILE][224];
  __shared__ int   sDst[TILE];

  const int g = tid >> 3, l = tid & 7;   // 8 threads per edge
  const int e   = order[s0 + g];
  const int dst = ei[e];
  const int src = ei[EE + e];
  if (l == 0) sDst[g] = dst;

  // ---- phase A: stage per-edge data ----
  *(float4*)&sEA[g][l * 4] = *(const float4*)(edge_attr + (size_t)e * 32 + l * 4);
  if (l == 1) *(float4*)&sSH[g][0] = *(const float4*)(edge_sh + (size_t)e * 4);
  {
    const float4* a4 = (const float4*)(x0nw + (size_t)src * 64 + l * 8);
    *(float4*)&sXS0[g][l * 8]     = a4[0];
    *(float4*)&sXS0[g][l * 8 + 4] = a4[1];
    const float4* b4 = (const float4*)(x1nw + (size_t)src * 96 + l * 12);
    *(float4*)&sXS1[g][l * 12]     = b4[0];
    *(float4*)&sXS1[g][l * 12 + 4] = b4[1];
    *(float4*)&sXS1[g][l * 12 + 8] = b4[2];
  }
  {
    const float4* pd = (const float4*)(p1w + (size_t)dst * 96 + l * 12);
    const float4* ps = (const float4*)(p1w + (size_t)src * 96 + l * 12);
    float dp[12], sp[12];
#pragma unroll
    for (int k = 0; k < 3; ++k) {
      float4 v = pd[k]; dp[4*k] = v.x; dp[4*k+1] = v.y; dp[4*k+2] = v.z; dp[4*k+3] = v.w;
      float4 u = ps[k]; sp[4*k] = u.x; sp[4*k+1] = u.y; sp[4*k+2] = u.z; sp[4*k+3] = u.w;
    }
#pragma unroll
    for (int vv = 0; vv < 4; ++vv) {
      const int b = 3 * vv;
      sIP[g][l * 4 + vv] =
        (dp[b] * sp[b] + dp[b+1] * sp[b+1] + dp[b+2] * sp[b+2]) * INVS3;
    }
  }
  __syncthreads();

  // ---- phase B: hidden layers (each thread: edge g, outputs l*4..l*4+3) ----
  {
    float hfa[4] = {0.f, 0.f, 0.f, 0.f};
    float hla[4] = {0.f, 0.f, 0.f, 0.f};
    for (int c = 0; c < 32; ++c) {
      const float eac = sEA[g][c];
      const float ipc = sIP[g][c];
      const float4 f  = *(const float4*)(F1 + c * 32 + l * 4);
      const float4 lc = *(const float4*)(L1 + (128 + c) * 32 + l * 4);
      hfa[0] = fmaf(eac, f.x, hfa[0]);  hfa[1] = fmaf(eac, f.y, hfa[1]);
      hfa[2] = fmaf(eac, f.z, hfa[2]);  hfa[3] = fmaf(eac, f.w, hfa[3]);
      hla[0] = fmaf(ipc, lc.x, hla[0]); hla[1] = fmaf(ipc, lc.y, hla[1]);
      hla[2] = fmaf(ipc, lc.z, hla[2]); hla[3] = fmaf(ipc, lc.w, hla[3]);
    }
    const float4 av = *(const float4*)(Aw + (size_t)dst * 32 + l * 4);
    const float4 bv = *(const float4*)(Bw + (size_t)src * 32 + l * 4);
    sHF[g][l*4+0] = sspf(hfa[0] * INVS32);
    sHF[g][l*4+1] = sspf(hfa[1] * INVS32);
    sHF[g][l*4+2] = sspf(hfa[2] * INVS32);
    sHF[g][l*4+3] = sspf(hfa[3] * INVS32);
    sHL[g][l*4+0] = sspf(av.x + bv.x + hla[0] * INVS160);
    sHL[g][l*4+1] = sspf(av.y + bv.y + hla[1] * INVS160);
    sHL[g][l*4+2] = sspf(av.z + bv.z + hla[2] * INVS160);
    sHL[g][l*4+3] = sspf(av.w + bv.w + hla[3] * INVS160);
  }
  __syncthreads();

  // ---- phase C: w = (hf@F2)*(hl@L2), scales folded, into LDS ----
  {
    const int cl = tid & 31, eg = tid >> 5;
    const int gb = eg * 4;                 // 4 edges per thread
    float aF[28], aL[28];
#pragma unroll
    for (int k = 0; k < 28; ++k) { aF[k] = 0.f; aL[k] = 0.f; }
    for (int i = 0; i < 32; ++i) {
      const float hf0 = sHF[gb+0][i], hf1 = sHF[gb+1][i];
      const float hf2 = sHF[gb+2][i], hf3 = sHF[gb+3][i];
      const float hl0 = sHL[gb+0][i], hl1 = sHL[gb+1][i];
      const float hl2 = sHL[gb+2][i], hl3 = sHL[gb+3][i];
      const float* F2r = F2 + i * 224;
      const float* L2r = L2 + i * 224;
#pragma unroll
      for (int cc = 0; cc < 7; ++cc) {
        const int c = cl + 32 * cc;
        const float f2  = F2r[c];
        const float l2v = L2r[c];
        aF[cc*4+0] = fmaf(hf0, f2, aF[cc*4+0]);
        aF[cc*4+1] = fmaf(hf1, f2, aF[cc*4+1]);
        aF[cc*4+2] = fmaf(hf2, f2, aF[cc*4+2]);
        aF[cc*4+3] = fmaf(hf3, f2, aF[cc*4+3]);
        aL[cc*4+0] = fmaf(hl0, l2v, aL[cc*4+0]);
        aL[cc*4+1] = fmaf(hl1, l2v, aL[cc*4+1]);
        aL[cc*4+2] = fmaf(hl2, l2v, aL[cc*4+2]);
        aL[cc*4+3] = fmaf(hl3, l2v, aL[cc*4+3]);
      }
    }
#pragma unroll
    for (int cc = 0; cc < 7; ++cc) {
      const int c = cl + 32 * cc;
      const float sc = ((c >= 64 && c < 128) || (c >= 160 && c < 192))
                         ? (INVS3 / 32.f)
                         : (c >= 192 ? (INVS2 / 32.f) : (1.f / 32.f));
#pragma unroll
      for (int q = 0; q < 4; ++q)
        sW[gb + q][c] = aF[cc*4+q] * aL[cc*4+q] * sc;
    }
  }
  __syncthreads();

  // ---- phase D: walk 32 sorted edges, accumulate, flush at dst boundaries ----
  {
    auto chan = [&](int q, int k) -> float {
      if (k < 64) {
        return sW[q][k] * sXS0[q][k] * sSH[q][0];
      } else if (k < 96) {
        const int c = k - 64;
        const float d = sXS1[q][c*3+0] * sSH[q][1]
                      + sXS1[q][c*3+1] * sSH[q][2]
                      + sXS1[q][c*3+2] * sSH[q][3];
        return sW[q][160 + c] * d;
      } else if (k < 288) {
        const int kk = k - 96; const int u = kk / 3; const int i = kk - 3 * u;
        return sW[q][64 + u] * sXS0[q][u] * sSH[q][1 + i];
      } else if (k < 384) {
        const int kk = k - 288; const int u = kk / 3; const int i = kk - 3 * u;
        return sW[q][128 + u] * sXS1[q][u * 3 + i] * sSH[q][0];
      } else {
        const int kk = k - 384; const int u = kk / 3; const int i = kk - 3 * u;
        const int i1 = (i + 1) % 3, i2 = (i + 2) % 3;
        const float cr = sXS1[q][u * 3 + i1] * sSH[q][1 + i2]
                       - sXS1[q][u * 3 + i2] * sSH[q][1 + i1];
        return sW[q][192 + u] * cr;
      }
    };

    float acc0 = 0.f, acc1 = 0.f;
    for (int q = 0; q < TILE; ++q) {
      acc0 += chan(q, tid);
      if (tid < 224) acc1 += chan(q, tid + 256);
      const bool boundary = (q == TILE - 1) || (sDst[q + 1] != sDst[q]);
      if (boundary) {
        float* dp = o480 + (size_t)sDst[q] * 480;
        atomicAdd(dp + tid, acc0);
        if (tid < 224) atomicAdd(dp + tid + 256, acc1);
        acc0 = 0.f; acc1 = 0.f;
      }
    }
  }
}

// ---------------- final output linears ----------------
__global__ __launch_bounds__(256) void out_wo_k(
    const float* __restrict__ o480,
    const float* __restrict__ WO0, const float* __restrict__ bO0,
    const float* __restrict__ WO1, const float* __restrict__ WO2,
    float* __restrict__ out)
{
  const int wv = threadIdx.x >> 6, lane = threadIdx.x & 63;
  const int n = blockIdx.x * 4 + wv;
  __shared__ float sO[4][480];
  if (n < NN) {
    for (int idx = lane; idx < 480; idx += 64)
      sO[wv][idx] = o480[(size_t)n * 480 + idx];
  }
  __syncthreads();
  if (n >= NN) return;
  for (int k = lane; k < 416; k += 64) {
    float y;
    if (k < 128) {
      float s = 0.f;
      for (int i = 0; i < 96; ++i) s += sO[wv][i] * WO0[i * 128 + k];
      y = s * INVS96 + bO0[k];
    } else if (k < 320) {
      const int kk = k - 128; const int v = kk / 3; const int i = kk - 3 * v;
      float s = 0.f;
      for (int u = 0; u < 96; ++u) s += sO[wv][96 + u * 3 + i] * WO1[u * 64 + v];
      y = s * INVS96;
    } else {
      const int kk = k - 320; const int v = kk / 3; const int i = kk - 3 * v;
      float s = 0.f;
      for (int u = 0; u < 32; ++u) s += sO[wv][384 + u * 3 + i] * WO2[u * 32 + v];
      y = s * INVS32;
    }
    out[(size_t)n * 416 + k] = y;
  }
}

// ---------------- host ----------------
extern "C" void kernel_launch(void* const* d_in, const int* in_sizes, int n_in,
                              void* d_out, int out_size, void* d_ws, size_t ws_size,
                              hipStream_t stream) {
  const float* x         = (const float*)d_in[0];
  const float* edge_sh   = (const float*)d_in[1];
  const float* edge_attr = (const float*)d_in[2];
  const float* W0p       = (const float*)d_in[3];
  const float* b0p       = (const float*)d_in[4];
  const float* W1p       = (const float*)d_in[5];
  const float* W0n       = (const float*)d_in[6];
  const float* b0n       = (const float*)d_in[7];
  const float* W1n       = (const float*)d_in[8];
  const float* G1        = (const float*)d_in[9];
  const float* g1b       = (const float*)d_in[10];
  const float* G2        = (const float*)d_in[11];
  const float* g2b       = (const float*)d_in[12];
  const float* F1        = (const float*)d_in[13];
  const float* F2        = (const float*)d_in[14];
  const float* L1        = (const float*)d_in[15];
  const float* L2        = (const float*)d_in[16];
  const float* WO0       = (const float*)d_in[17];
  const float* bO0       = (const float*)d_in[18];
  const float* WO1       = (const float*)d_in[19];
  const float* WO2       = (const float*)d_in[20];
  const int*   ei        = (const int*)d_in[21];
  float* out = (float*)d_out;

  float* p1w  = (float*)d_ws;          // N*96
  float* x0nw = p1w  + NN * 96;        // N*64
  float* x1nw = x0nw + NN * 64;        // N*96
  float* Aw   = x1nw + NN * 96;        // N*32
  float* Bw   = Aw   + NN * 32;        // N*32
  float* o480 = Bw   + NN * 32;        // N*480
  int* cnt    = (int*)(o480 + NN * 480);
  int* offv   = cnt    + NN;           // N+1
  int* cursor = offv   + NN + 1;       // N
  int* order  = cursor + NN;           // E

  hipMemsetAsync(cnt, 0, NN * sizeof(int), stream);
  hipMemsetAsync(o480, 0, (size_t)NN * 480 * sizeof(float), stream);
  hist_k<<<(EE + 255) / 256, 256, 0, stream>>>(ei, cnt);
  scan_k<<<1, 1024, 0, stream>>>(cnt, offv, cursor);
  scat_k<<<(EE + 255) / 256, 256, 0, stream>>>(ei, cursor, order);
  node_prep_k<<<(NN + 3) / 4, 256, 0, stream>>>(x, W0p, b0p, W1p, W0n, b0n, W1n,
                                                G1, g1b, G2, g2b, L1,
                                                p1w, x0nw, x1nw, Aw, Bw);
  fused_edge_k<<<EE / TILE, 256, 0, stream>>>(edge_attr, edge_sh, ei,
                                              F1, L1, F2, L2,
                                              p1w, Aw, Bw, x0nw, x1nw,
                                              order, o480);
  out_wo_k<<<NN / 4, 256, 0, stream>>>(o480, WO0, bO0, WO1, WO2, out);
}

// Round 4
// 556.123 us; speedup vs baseline: 1.5564x; 1.5564x over previous
//
#include <hip/hip_runtime.h>
#include <math.h>

#define NN 10000
#define EE 320000
#define TILE 32

constexpr float INVS32  = 0.17677669529663687f;   // 1/sqrt(32)
constexpr float INVS160 = 0.07905694150420949f;   // 1/sqrt(160)
constexpr float INVS96  = 0.10206207261596575f;   // 1/sqrt(96)
constexpr float INVS3   = 0.5773502691896258f;    // 1/sqrt(3)
constexpr float INVS2   = 0.7071067811865476f;    // 1/sqrt(2)
constexpr float LN2     = 0.6931471805599453f;

typedef short bf16x8 __attribute__((ext_vector_type(8)));
typedef float f32x4  __attribute__((ext_vector_type(4)));

__device__ __forceinline__ float sspf(float v) {
  return fmaxf(v, 0.f) + log1pf(expf(-fabsf(v))) - LN2;
}
__device__ __forceinline__ ushort f2bf(float f) {
  union { float f; unsigned u; } v; v.f = f;
  unsigned r = v.u + 0x7FFF + ((v.u >> 16) & 1);   // RNE
  return (ushort)(r >> 16);
}
__device__ __forceinline__ float bf2f(ushort u) {
  return __uint_as_float(((unsigned)u) << 16);
}
__device__ __forceinline__ unsigned pk(float a, float b) {
  return (unsigned)f2bf(a) | ((unsigned)f2bf(b) << 16);
}

// ---------------- sort-by-dst kernels ----------------
__global__ void hist_k(const int* __restrict__ ei, int* __restrict__ cnt) {
  int e = blockIdx.x * 256 + threadIdx.x;
  if (e < EE) atomicAdd(&cnt[ei[e]], 1);
}

__global__ __launch_bounds__(1024) void scan_k(const int* __restrict__ cnt,
                                               int* __restrict__ offv,
                                               int* __restrict__ cursor) {
  __shared__ int s[1024];
  const int t = threadIdx.x;
  int loc[10];
  int sum = 0;
#pragma unroll
  for (int jj = 0; jj < 10; ++jj) {
    int idx = t * 10 + jj;
    int c = (idx < NN) ? cnt[idx] : 0;
    loc[jj] = sum;
    sum += c;
  }
  s[t] = sum;
  __syncthreads();
  for (int d = 1; d < 1024; d <<= 1) {
    int v = (t >= d) ? s[t - d] : 0;
    __syncthreads();
    s[t] += v;
    __syncthreads();
  }
  const int excl = (t > 0) ? s[t - 1] : 0;
#pragma unroll
  for (int jj = 0; jj < 10; ++jj) {
    int idx = t * 10 + jj;
    if (idx < NN) {
      offv[idx]   = excl + loc[jj];
      cursor[idx] = excl + loc[jj];
    }
  }
  if (t == 0) offv[NN] = EE;
}

__global__ void scat_k(const int* __restrict__ ei, int* __restrict__ cursor,
                       int* __restrict__ order) {
  int e = blockIdx.x * 256 + threadIdx.x;
  if (e < EE) {
    int p = atomicAdd(&cursor[ei[e]], 1);
    order[p] = e;
  }
}

// ---------------- weight transpose/convert: F2T,L2T bf16, scale folded ----------------
__global__ void prep_t_k(const float* __restrict__ F2, const float* __restrict__ L2,
                         ushort* __restrict__ F2Tb, ushort* __restrict__ L2Tb) {
  int i = blockIdx.x * 256 + threadIdx.x;   // over 224*32
  if (i < 224 * 32) {
    int c = i >> 5, k = i & 31;
    float sc = (c < 64)  ? (1.f / 32.f)
             : (c < 128) ? (INVS3 / 32.f)
             : (c < 160) ? (1.f / 32.f)
             : (c < 192) ? (INVS3 / 32.f)
                         : (INVS2 / 32.f);
    F2Tb[i] = f2bf(F2[k * 224 + c] * sc);
    L2Tb[i] = f2bf(L2[k * 224 + c]);
  }
}

// ---------------- node-level precompute ----------------
__global__ __launch_bounds__(256) void node_prep_k(
    const float* __restrict__ x,
    const float* __restrict__ W0p, const float* __restrict__ b0p,
    const float* __restrict__ W1p,
    const float* __restrict__ W0n, const float* __restrict__ b0n,
    const float* __restrict__ W1n,
    const float* __restrict__ G1, const float* __restrict__ g1b,
    const float* __restrict__ G2, const float* __restrict__ g2b,
    const float* __restrict__ L1,
    float* __restrict__ p1w, float* __restrict__ x0nw, float* __restrict__ x1nw,
    float* __restrict__ Aw, float* __restrict__ Bw)
{
  const int wv   = threadIdx.x >> 6;
  const int lane = threadIdx.x & 63;
  const int n    = blockIdx.x * 4 + wv;
  const bool nv  = (n < NN);

  __shared__ float sX[4][160];
  __shared__ float sP0[4][64];
  __shared__ float sF0[4][96];
  __shared__ float sH1[4][96];
  __shared__ float sG[4][96];

  if (nv) {
    sX[wv][lane]      = x[n * 160 + lane];
    sX[wv][lane + 64] = x[n * 160 + lane + 64];
    if (lane < 32) sX[wv][lane + 128] = x[n * 160 + lane + 128];
  }
  __syncthreads();

  if (nv) {
    {
      float d = 0.f;
      for (int i = 0; i < 64; ++i) d += sX[wv][i] * W0p[i * 64 + lane];
      sP0[wv][lane] = d * 0.125f + b0p[lane];
      sF0[wv][lane] = sX[wv][lane];
    }
    for (int o = lane; o < 96; o += 64) {
      const int v = o / 3, i_ = o % 3;
      float d = 0.f;
      for (int u = 0; u < 32; ++u) d += sX[wv][64 + u * 3 + i_] * W1p[u * 32 + v];
      p1w[n * 96 + o] = d * INVS32;
    }
    if (lane < 32) {
      float s2 = 1e-12f;
#pragma unroll
      for (int i = 0; i < 3; ++i) { float t = sX[wv][64 + lane * 3 + i]; s2 += t * t; }
      sF0[wv][64 + lane] = sqrtf(s2);
    }
  }
  __syncthreads();

  if (nv) for (int o = lane; o < 96; o += 64) {
    float d = g1b[o];
    for (int i = 0; i < 96; ++i) d += sF0[wv][i] * G1[i * 96 + o];
    sH1[wv][o] = d / (1.f + expf(-d));
  }
  __syncthreads();

  if (nv) for (int o = lane; o < 96; o += 64) {
    float d = g2b[o];
    for (int i = 0; i < 96; ++i) d += sH1[wv][i] * G2[i * 96 + o];
    sG[wv][o] = d;
  }
  __syncthreads();

  if (nv) {
    {
      float d = 0.f;
      for (int i = 0; i < 64; ++i) d += sG[wv][i] * W0n[i * 64 + lane];
      x0nw[n * 64 + lane] = d * 0.125f + b0n[lane];
    }
    for (int o = lane; o < 96; o += 64) {
      const int v = o / 3, i_ = o % 3;
      float d = 0.f;
      for (int u = 0; u < 32; ++u)
        d += sX[wv][64 + u * 3 + i_] * sG[wv][64 + u] * W1n[u * 32 + v];
      x1nw[n * 96 + o] = d * INVS32;
    }
    if (lane < 32) {
      float a = 0.f, b = 0.f;
      for (int i = 0; i < 64; ++i) {
        a += sP0[wv][i] * L1[i * 32 + lane];
        b += sP0[wv][i] * L1[(64 + i) * 32 + lane];
      }
      Aw[n * 32 + lane] = a * INVS160;
      Bw[n * 32 + lane] = b * INVS160;
    }
  }
}

// ---------------- fused per-edge MLP (MFMA) + scatter kernel ----------------
__global__ __launch_bounds__(256, 4) void fused_edge_k(
    const float* __restrict__ edge_attr,
    const float* __restrict__ edge_sh,
    const int* __restrict__ ei,
    const float* __restrict__ F1, const float* __restrict__ L1,
    const ushort* __restrict__ F2Tb, const ushort* __restrict__ L2Tb,
    const float* __restrict__ p1w, const float* __restrict__ Aw,
    const float* __restrict__ Bw,
    const float* __restrict__ x0nw, const float* __restrict__ x1nw,
    const int* __restrict__ order,
    float* __restrict__ o480)
{
  const int s0  = blockIdx.x * TILE;
  const int tid = threadIdx.x;

  // union region: sW (bf16 32x224) overlaps sEA/sIP (f32 32x36, dead after B)
  __shared__ __align__(16) char uMem[32 * 224 * 2];          // 14336 B
  ushort (*sW)[224] = (ushort (*)[224])uMem;
  float  (*sEA)[36] = (float (*)[36])uMem;                   // 4608 B
  float  (*sIP)[36] = (float (*)[36])(uMem + 32 * 36 * 4);   // 4608 B

  __shared__ ushort sHF[32][40];    // bf16, 80B row stride (2-way banks)
  __shared__ ushort sHL[32][40];
  __shared__ ushort sXS0[32][64];   // bf16
  __shared__ ushort sXS1[32][96];   // bf16
  __shared__ float  sSH[32][4];
  __shared__ int    sDst[32];

  const int g = tid >> 3, l = tid & 7;   // 8 threads per edge
  const int e   = order[s0 + g];
  const int dst = ei[e];
  const int src = ei[EE + e];
  if (l == 0) sDst[g] = dst;

  // ---- phase A: stage per-edge data ----
  *(float4*)&sEA[g][l * 4] = *(const float4*)(edge_attr + (size_t)e * 32 + l * 4);
  if (l == 1) *(float4*)&sSH[g][0] = *(const float4*)(edge_sh + (size_t)e * 4);
  {
    const float4* a4 = (const float4*)(x0nw + (size_t)src * 64 + l * 8);
    float4 v0 = a4[0], v1 = a4[1];
    *(unsigned*)&sXS0[g][l * 8 + 0] = pk(v0.x, v0.y);
    *(unsigned*)&sXS0[g][l * 8 + 2] = pk(v0.z, v0.w);
    *(unsigned*)&sXS0[g][l * 8 + 4] = pk(v1.x, v1.y);
    *(unsigned*)&sXS0[g][l * 8 + 6] = pk(v1.z, v1.w);
    const float4* b4 = (const float4*)(x1nw + (size_t)src * 96 + l * 12);
    float4 w0 = b4[0], w1 = b4[1], w2 = b4[2];
    *(unsigned*)&sXS1[g][l * 12 + 0]  = pk(w0.x, w0.y);
    *(unsigned*)&sXS1[g][l * 12 + 2]  = pk(w0.z, w0.w);
    *(unsigned*)&sXS1[g][l * 12 + 4]  = pk(w1.x, w1.y);
    *(unsigned*)&sXS1[g][l * 12 + 6]  = pk(w1.z, w1.w);
    *(unsigned*)&sXS1[g][l * 12 + 8]  = pk(w2.x, w2.y);
    *(unsigned*)&sXS1[g][l * 12 + 10] = pk(w2.z, w2.w);
  }
  {
    const float4* pd = (const float4*)(p1w + (size_t)dst * 96 + l * 12);
    const float4* ps = (const float4*)(p1w + (size_t)src * 96 + l * 12);
    float dp[12], sp[12];
#pragma unroll
    for (int k = 0; k < 3; ++k) {
      float4 v = pd[k]; dp[4*k] = v.x; dp[4*k+1] = v.y; dp[4*k+2] = v.z; dp[4*k+3] = v.w;
      float4 u = ps[k]; sp[4*k] = u.x; sp[4*k+1] = u.y; sp[4*k+2] = u.z; sp[4*k+3] = u.w;
    }
#pragma unroll
    for (int vv = 0; vv < 4; ++vv) {
      const int b = 3 * vv;
      sIP[g][l * 4 + vv] =
        (dp[b] * sp[b] + dp[b+1] * sp[b+1] + dp[b+2] * sp[b+2]) * INVS3;
    }
  }
  __syncthreads();

  // ---- phase B: hidden layers -> bf16 LDS ----
  {
    float hfa[4] = {0.f, 0.f, 0.f, 0.f};
    float hla[4] = {0.f, 0.f, 0.f, 0.f};
    for (int c = 0; c < 32; ++c) {
      const float eac = sEA[g][c];
      const float ipc = sIP[g][c];
      const float4 f  = *(const float4*)(F1 + c * 32 + l * 4);
      const float4 lc = *(const float4*)(L1 + (128 + c) * 32 + l * 4);
      hfa[0] = fmaf(eac, f.x, hfa[0]);  hfa[1] = fmaf(eac, f.y, hfa[1]);
      hfa[2] = fmaf(eac, f.z, hfa[2]);  hfa[3] = fmaf(eac, f.w, hfa[3]);
      hla[0] = fmaf(ipc, lc.x, hla[0]); hla[1] = fmaf(ipc, lc.y, hla[1]);
      hla[2] = fmaf(ipc, lc.z, hla[2]); hla[3] = fmaf(ipc, lc.w, hla[3]);
    }
    const float4 av = *(const float4*)(Aw + (size_t)dst * 32 + l * 4);
    const float4 bv = *(const float4*)(Bw + (size_t)src * 32 + l * 4);
    const float f0 = sspf(hfa[0] * INVS32), f1 = sspf(hfa[1] * INVS32);
    const float f2 = sspf(hfa[2] * INVS32), f3 = sspf(hfa[3] * INVS32);
    const float l0 = sspf(av.x + bv.x + hla[0] * INVS160);
    const float l1v = sspf(av.y + bv.y + hla[1] * INVS160);
    const float l2v = sspf(av.z + bv.z + hla[2] * INVS160);
    const float l3v = sspf(av.w + bv.w + hla[3] * INVS160);
    *(unsigned*)&sHF[g][l * 4 + 0] = pk(f0, f1);
    *(unsigned*)&sHF[g][l * 4 + 2] = pk(f2, f3);
    *(unsigned*)&sHL[g][l * 4 + 0] = pk(l0, l1v);
    *(unsigned*)&sHL[g][l * 4 + 2] = pk(l2v, l3v);
  }
  __syncthreads();

  // ---- phase C: MFMA w-GEMMs: [32x32]@[32x224] x2, w = Wf.*Wl (bf16 out) ----
  {
    const int wv   = tid >> 6;
    const int lane = tid & 63;
    const int r = lane & 15;   // A row / B col within tile
    const int h = lane >> 4;   // k-offset h*8
    bf16x8 aF0 = *(const bf16x8*)&sHF[r][h * 8];
    bf16x8 aF1 = *(const bf16x8*)&sHF[16 + r][h * 8];
    bf16x8 aL0 = *(const bf16x8*)&sHL[r][h * 8];
    bf16x8 aL1 = *(const bf16x8*)&sHL[16 + r][h * 8];
    const int ct0 = (wv < 2) ? wv * 4 : 8 + (wv - 2) * 3;
    const int nct = (wv < 2) ? 4 : 3;
    for (int t = 0; t < nct; ++t) {
      const int ct = ct0 + t;
      const int c  = ct * 16 + r;
      bf16x8 bF = *(const bf16x8*)&F2Tb[c * 32 + h * 8];
      bf16x8 bL = *(const bf16x8*)&L2Tb[c * 32 + h * 8];
      f32x4 z = {0.f, 0.f, 0.f, 0.f};
      f32x4 wf0 = __builtin_amdgcn_mfma_f32_16x16x32_bf16(aF0, bF, z, 0, 0, 0);
      f32x4 wl0 = __builtin_amdgcn_mfma_f32_16x16x32_bf16(aL0, bL, z, 0, 0, 0);
      f32x4 wf1 = __builtin_amdgcn_mfma_f32_16x16x32_bf16(aF1, bF, z, 0, 0, 0);
      f32x4 wl1 = __builtin_amdgcn_mfma_f32_16x16x32_bf16(aL1, bL, z, 0, 0, 0);
#pragma unroll
      for (int i = 0; i < 4; ++i) {
        sW[h * 4 + i][c]      = f2bf(wf0[i] * wl0[i]);
        sW[16 + h * 4 + i][c] = f2bf(wf1[i] * wl1[i]);
      }
    }
  }
  __syncthreads();

  // ---- phase D: walk 32 sorted edges, accumulate, flush at dst boundaries ----
  {
    auto chan = [&](int q, int k) -> float {
      if (k < 64) {
        return bf2f(sW[q][k]) * bf2f(sXS0[q][k]) * sSH[q][0];
      } else if (k < 96) {
        const int c = k - 64;
        const float d = bf2f(sXS1[q][c*3+0]) * sSH[q][1]
                      + bf2f(sXS1[q][c*3+1]) * sSH[q][2]
                      + bf2f(sXS1[q][c*3+2]) * sSH[q][3];
        return bf2f(sW[q][160 + c]) * d;
      } else if (k < 288) {
        const int kk = k - 96; const int u = kk / 3; const int i = kk - 3 * u;
        return bf2f(sW[q][64 + u]) * bf2f(sXS0[q][u]) * sSH[q][1 + i];
      } else if (k < 384) {
        const int kk = k - 288; const int u = kk / 3; const int i = kk - 3 * u;
        return bf2f(sW[q][128 + u]) * bf2f(sXS1[q][u * 3 + i]) * sSH[q][0];
      } else {
        const int kk = k - 384; const int u = kk / 3; const int i = kk - 3 * u;
        const int i1 = (i + 1) % 3, i2 = (i + 2) % 3;
        const float cr = bf2f(sXS1[q][u * 3 + i1]) * sSH[q][1 + i2]
                       - bf2f(sXS1[q][u * 3 + i2]) * sSH[q][1 + i1];
        return bf2f(sW[q][192 + u]) * cr;
      }
    };

    float acc0 = 0.f, acc1 = 0.f;
    for (int q = 0; q < TILE; ++q) {
      acc0 += chan(q, tid);
      if (tid < 224) acc1 += chan(q, tid + 256);
      const bool boundary = (q == TILE - 1) || (sDst[q + 1] != sDst[q]);
      if (boundary) {
        float* dp = o480 + (size_t)sDst[q] * 480;
        atomicAdd(dp + tid, acc0);
        if (tid < 224) atomicAdd(dp + tid + 256, acc1);
        acc0 = 0.f; acc1 = 0.f;
      }
    }
  }
}

// ---------------- final output linears ----------------
__global__ __launch_bounds__(256) void out_wo_k(
    const float* __restrict__ o480,
    const float* __restrict__ WO0, const float* __restrict__ bO0,
    const float* __restrict__ WO1, const float* __restrict__ WO2,
    float* __restrict__ out)
{
  const int wv = threadIdx.x >> 6, lane = threadIdx.x & 63;
  const int n = blockIdx.x * 4 + wv;
  __shared__ float sO[4][480];
  if (n < NN) {
    for (int idx = lane; idx < 480; idx += 64)
      sO[wv][idx] = o480[(size_t)n * 480 + idx];
  }
  __syncthreads();
  if (n >= NN) return;
  for (int k = lane; k < 416; k += 64) {
    float y;
    if (k < 128) {
      float s = 0.f;
      for (int i = 0; i < 96; ++i) s += sO[wv][i] * WO0[i * 128 + k];
      y = s * INVS96 + bO0[k];
    } else if (k < 320) {
      const int kk = k - 128; const int v = kk / 3; const int i = kk - 3 * v;
      float s = 0.f;
      for (int u = 0; u < 96; ++u) s += sO[wv][96 + u * 3 + i] * WO1[u * 64 + v];
      y = s * INVS96;
    } else {
      const int kk = k - 320; const int v = kk / 3; const int i = kk - 3 * v;
      float s = 0.f;
      for (int u = 0; u < 32; ++u) s += sO[wv][384 + u * 3 + i] * WO2[u * 32 + v];
      y = s * INVS32;
    }
    out[(size_t)n * 416 + k] = y;
  }
}

// ---------------- host ----------------
extern "C" void kernel_launch(void* const* d_in, const int* in_sizes, int n_in,
                              void* d_out, int out_size, void* d_ws, size_t ws_size,
                              hipStream_t stream) {
  const float* x         = (const float*)d_in[0];
  const float* edge_sh   = (const float*)d_in[1];
  const float* edge_attr = (const float*)d_in[2];
  const float* W0p       = (const float*)d_in[3];
  const float* b0p       = (const float*)d_in[4];
  const float* W1p       = (const float*)d_in[5];
  const float* W0n       = (const float*)d_in[6];
  const float* b0n       = (const float*)d_in[7];
  const float* W1n       = (const float*)d_in[8];
  const float* G1        = (const float*)d_in[9];
  const float* g1b       = (const float*)d_in[10];
  const float* G2        = (const float*)d_in[11];
  const float* g2b       = (const float*)d_in[12];
  const float* F1        = (const float*)d_in[13];
  const float* F2        = (const float*)d_in[14];
  const float* L1        = (const float*)d_in[15];
  const float* L2        = (const float*)d_in[16];
  const float* WO0       = (const float*)d_in[17];
  const float* bO0       = (const float*)d_in[18];
  const float* WO1       = (const float*)d_in[19];
  const float* WO2       = (const float*)d_in[20];
  const int*   ei        = (const int*)d_in[21];
  float* out = (float*)d_out;

  float* p1w  = (float*)d_ws;          // N*96
  float* x0nw = p1w  + NN * 96;        // N*64
  float* x1nw = x0nw + NN * 64;        // N*96
  float* Aw   = x1nw + NN * 96;        // N*32
  float* Bw   = Aw   + NN * 32;        // N*32
  float* o480 = Bw   + NN * 32;        // N*480
  int* cnt    = (int*)(o480 + (size_t)NN * 480);
  int* offv   = cnt    + NN;           // N+1
  int* cursor = offv   + NN + 1;       // N
  int* order  = cursor + NN;           // E
  uintptr_t p = (uintptr_t)(order + EE);
  p = (p + 15) & ~(uintptr_t)15;
  ushort* F2Tb = (ushort*)p;           // 224*32 bf16
  ushort* L2Tb = F2Tb + 224 * 32;

  hipMemsetAsync(cnt, 0, NN * sizeof(int), stream);
  hipMemsetAsync(o480, 0, (size_t)NN * 480 * sizeof(float), stream);
  prep_t_k<<<28, 256, 0, stream>>>(F2, L2, F2Tb, L2Tb);
  hist_k<<<(EE + 255) / 256, 256, 0, stream>>>(ei, cnt);
  scan_k<<<1, 1024, 0, stream>>>(cnt, offv, cursor);
  scat_k<<<(EE + 255) / 256, 256, 0, stream>>>(ei, cursor, order);
  node_prep_k<<<(NN + 3) / 4, 256, 0, stream>>>(x, W0p, b0p, W1p, W0n, b0n, W1n,
                                                G1, g1b, G2, g2b, L1,
                                                p1w, x0nw, x1nw, Aw, Bw);
  fused_edge_k<<<EE / TILE, 256, 0, stream>>>(edge_attr, edge_sh, ei,
                                              F1, L1, F2Tb, L2Tb,
                                              p1w, Aw, Bw, x0nw, x1nw,
                                              order, o480);
  out_wo_k<<<NN / 4, 256, 0, stream>>>(o480, WO0, bO0, WO1, WO2, out);
}